// Round 1
// baseline (332.854 us; speedup 1.0000x reference)
//
#include <hip/hip_runtime.h>
#include <math.h>

// Problem constants: b=4, f=64, h=w=64, HW=4096
// Inputs: fdm [4,1,128,128], x [4,64,64,64], W_fuse [64,128,3,3], b_fuse [64], gamma [64], beta [64]
// Outputs concatenated: x0 [4,64,64,64] (1048576 f32) then sm [4,1,64,64] (16384 f32)

#define HW 4096
#define NCH 64
#define BATCH 4

// ---------------- K1: 2x2 max pool + per-batch max + threshold + sel/unsel compaction ----------------
__global__ void k_pool(const float* __restrict__ fdm, int* __restrict__ sel, int* __restrict__ unsel,
                       int* __restrict__ selN, int* __restrict__ unselN,
                       float* __restrict__ gnS1, float* __restrict__ gnS2) {
    const int b = blockIdx.x;
    const int t = threadIdx.x;
    __shared__ float pooled[4096];
    __shared__ float red[256];
    __shared__ int cnt[2];
    __shared__ float thre_s;
    const float* fb = fdm + b * 16384;
    float lmax = -1.0f;
    for (int idx = t; idx < 4096; idx += 256) {
        int i = idx >> 6, j = idx & 63;
        const float* r0 = fb + i * 256 + j * 2;   // (2i)*128 + 2j
        float v = fmaxf(fmaxf(r0[0], r0[1]), fmaxf(r0[128], r0[129]));
        pooled[idx] = v;
        lmax = fmaxf(lmax, v);
    }
    red[t] = lmax;
    __syncthreads();
    for (int s = 128; s > 0; s >>= 1) {
        if (t < s) red[t] = fmaxf(red[t], red[t + s]);
        __syncthreads();
    }
    if (t == 0) {
        thre_s = fminf(0.5f, red[0] / 3.0f);  // match reference rounding exactly
        cnt[0] = 0; cnt[1] = 0;
        gnS1[b] = 0.0f; gnS2[b] = 0.0f;       // zero GN accumulators (ws is poisoned)
    }
    __syncthreads();
    const float th = thre_s;
    for (int idx = t; idx < 4096; idx += 256) {
        if (pooled[idx] >= th) {
            int pos = atomicAdd(&cnt[0], 1);
            sel[b * 4096 + pos] = idx;
        } else {
            int pos = atomicAdd(&cnt[1], 1);
            unsel[b * 4096 + pos] = idx;
        }
    }
    __syncthreads();
    if (t == 0) { selN[b] = cnt[0]; unselN[b] = cnt[1]; }
}

// ---------------- K2: per-position inverse norms + default sm = 1.0 ----------------
__global__ void k_norm(const float* __restrict__ x, float* __restrict__ rn, float* __restrict__ smOut) {
    const int g = blockIdx.x * 256 + threadIdx.x;   // 0..16383
    const int b = g >> 12;
    const int p = g & 4095;
    const float* xp = x + b * (NCH * HW) + p;
    float s0 = 0.f, s1 = 0.f, s2 = 0.f, s3 = 0.f;
#pragma unroll
    for (int c = 0; c < 64; c += 4) {
        float a0 = xp[(c + 0) * HW];
        float a1 = xp[(c + 1) * HW];
        float a2 = xp[(c + 2) * HW];
        float a3 = xp[(c + 3) * HW];
        s0 += a0 * a0; s1 += a1 * a1; s2 += a2 * a2; s3 += a3 * a3;
    }
    float ss = (s0 + s1) + (s2 + s3);
    rn[g] = 1.0f / fmaxf(sqrtf(ss), 1e-8f);
    smOut[g] = 1.0f;   // selected positions: diag cosine = 1 -> sm = 1/2+1/2 = 1
}

// ---------------- K3: for unselected q, sm = (max over selected p of cos)/2 + 0.5 ----------------
__global__ void k_cosmax(const float* __restrict__ x, const float* __restrict__ rn,
                         const int* __restrict__ sel, const int* __restrict__ unsel,
                         const int* __restrict__ selN, const int* __restrict__ unselN,
                         float* __restrict__ smOut) {
    const int b = blockIdx.y;
    const int lane = threadIdx.x & 63;
    const int wid = blockIdx.x * 4 + (threadIdx.x >> 6);   // wave id in batch, 0..63
    const float* xb = x + b * (NCH * HW);
    const float* rb = rn + b * HW;
    const int* selb = sel + b * 4096;
    const int ns = selN[b];
    const int nu = unselN[b];
    for (int qi = wid; qi < nu; qi += 64) {
        const int q = unsel[b * 4096 + qi];
        // broadcast x[:, q] to all lanes into a register array
        float own = xb[lane * HW + q];
        float xq[64];
#pragma unroll
        for (int c = 0; c < 64; ++c) xq[c] = __shfl(own, c);
        float best = -INFINITY;
        for (int base = 0; base < ns; base += 64) {
            int i = base + lane;
            bool valid = (i < ns);
            int p = valid ? selb[i] : selb[0];
            float rp = rb[p];
            const float* xp = xb + p;
            float d0 = 0.f, d1 = 0.f, d2 = 0.f, d3 = 0.f;
#pragma unroll
            for (int c = 0; c < 64; c += 4) {
                d0 += xp[(c + 0) * HW] * xq[c + 0];
                d1 += xp[(c + 1) * HW] * xq[c + 1];
                d2 += xp[(c + 2) * HW] * xq[c + 2];
                d3 += xp[(c + 3) * HW] * xq[c + 3];
            }
            float dot = (d0 + d1) + (d2 + d3);
            float score = valid ? dot * rp : -INFINITY;
            best = fmaxf(best, score);
        }
#pragma unroll
        for (int off = 32; off > 0; off >>= 1) best = fmaxf(best, __shfl_xor(best, off));
        if (lane == 0) {
            float rq = rb[q];
            smOut[b * 4096 + q] = best * rq * 0.5f + 0.5f;
        }
    }
}

// ---------------- K4: direct conv 3x3 (128->64) + bias, with GN partial sums via atomics ----------------
// grid: (h=64, split=2, b=4); block 256. Each block: 32 oc x 64 w for one row h.
// Thread: 2 oc x 4 w. ic chunks of 16 staged in LDS.
__global__ __launch_bounds__(256) void k_conv(const float* __restrict__ x, const float* __restrict__ W,
                                              const float* __restrict__ bfuse, const float* __restrict__ smAll,
                                              float* __restrict__ y, float* __restrict__ gnS1, float* __restrict__ gnS2) {
    const int h = blockIdx.x;
    const int split = blockIdx.y;
    const int b = blockIdx.z;
    __shared__ float in_t[16][3][68];     // ic x row x (66 cols, padded to 68 for 16B row alignment)
    __shared__ float w_t[32][196];        // [oc][ic*12 + k], stride 196 floats to dodge bank conflicts
    __shared__ float red1[256];
    __shared__ float red2[256];
    const int t = threadIdx.x;
    const int w4 = (t & 15) * 4;
    const int ocl = (t >> 4) * 2;
    const int ocg = split * 32 + ocl;
    const float* xb = x + b * (NCH * HW);
    const float* smb = smAll + b * HW;

    float acc0[4], acc1[4];
    const float bi0 = bfuse[ocg], bi1 = bfuse[ocg + 1];
#pragma unroll
    for (int j = 0; j < 4; ++j) { acc0[j] = bi0; acc1[j] = bi1; }

    for (int chunk = 0; chunk < 8; ++chunk) {
        __syncthreads();
        // stage input tile: cat channel icg = chunk*16+ic; rows h-1..h+1; cols -1..64
        for (int idx = t; idx < 3168; idx += 256) {
            int ic = idx / 198;
            int rem = idx - ic * 198;
            int r = rem / 66;
            int tc = rem - r * 66;
            int icg = chunk * 16 + ic;
            int hh = h + r - 1;
            int cin = tc - 1;
            float v = 0.0f;
            if ((unsigned)hh < 64u && (unsigned)cin < 64u) {
                int sp = hh * 64 + cin;
                v = (icg < 64) ? smb[sp] * xb[icg * HW + sp] : xb[(icg - 64) * HW + sp];
            }
            in_t[ic][r][tc] = v;
        }
        // stage weights: 32 oc x 16 ic x 9
        for (int idx = t; idx < 4608; idx += 256) {
            int oc = idx / 144;
            int rem = idx - oc * 144;
            int ic = rem / 9;
            int k = rem - ic * 9;
            w_t[oc][ic * 12 + k] = W[(split * 32 + oc) * 1152 + (chunk * 16 + ic) * 9 + k];
        }
        __syncthreads();
#pragma unroll
        for (int ic = 0; ic < 16; ++ic) {
            float iv[3][6];
#pragma unroll
            for (int r = 0; r < 3; ++r) {
                const float* row = &in_t[ic][r][0];
                float4 v = *(const float4*)(row + w4);
                iv[r][0] = v.x; iv[r][1] = v.y; iv[r][2] = v.z; iv[r][3] = v.w;
                iv[r][4] = row[w4 + 4]; iv[r][5] = row[w4 + 5];
            }
            float wv0[9], wv1[9];
            {
                const float* wp = &w_t[ocl][ic * 12];
                float4 a = *(const float4*)wp;
                float4 bq = *(const float4*)(wp + 4);
                wv0[0] = a.x; wv0[1] = a.y; wv0[2] = a.z; wv0[3] = a.w;
                wv0[4] = bq.x; wv0[5] = bq.y; wv0[6] = bq.z; wv0[7] = bq.w;
                wv0[8] = wp[8];
            }
            {
                const float* wp = &w_t[ocl + 1][ic * 12];
                float4 a = *(const float4*)wp;
                float4 bq = *(const float4*)(wp + 4);
                wv1[0] = a.x; wv1[1] = a.y; wv1[2] = a.z; wv1[3] = a.w;
                wv1[4] = bq.x; wv1[5] = bq.y; wv1[6] = bq.z; wv1[7] = bq.w;
                wv1[8] = wp[8];
            }
#pragma unroll
            for (int r = 0; r < 3; ++r) {
#pragma unroll
                for (int s = 0; s < 3; ++s) {
                    float w0 = wv0[r * 3 + s];
                    float w1 = wv1[r * 3 + s];
#pragma unroll
                    for (int j = 0; j < 4; ++j) {
                        acc0[j] += w0 * iv[r][j + s];
                        acc1[j] += w1 * iv[r][j + s];
                    }
                }
            }
        }
    }
    // write y and reduce GN partials
    const int sp = h * 64 + w4;
    float4 o0 = make_float4(acc0[0], acc0[1], acc0[2], acc0[3]);
    float4 o1 = make_float4(acc1[0], acc1[1], acc1[2], acc1[3]);
    *(float4*)(y + (b * 64 + ocg) * HW + sp) = o0;
    *(float4*)(y + (b * 64 + ocg + 1) * HW + sp) = o1;
    float s1 = 0.f, s2 = 0.f;
#pragma unroll
    for (int j = 0; j < 4; ++j) {
        s1 += acc0[j] + acc1[j];
        s2 += acc0[j] * acc0[j] + acc1[j] * acc1[j];
    }
    red1[t] = s1; red2[t] = s2;
    __syncthreads();
    for (int s = 128; s > 0; s >>= 1) {
        if (t < s) { red1[t] += red1[t + s]; red2[t] += red2[t + s]; }
        __syncthreads();
    }
    if (t == 0) {
        atomicAdd(&gnS1[b], red1[0]);
        atomicAdd(&gnS2[b], red2[0]);
    }
}

// ---------------- K5: GroupNorm(1 group) + affine + ReLU ----------------
__global__ void k_gn(const float* __restrict__ y, const float* __restrict__ gnS1, const float* __restrict__ gnS2,
                     const float* __restrict__ gamma, const float* __restrict__ beta, float* __restrict__ out) {
    const int e = (blockIdx.x * 256 + threadIdx.x) * 4;   // element index into [4,64,64,64] flat
    const int b = e >> 18;
    const int c = (e >> 12) & 63;
    const float inv = 1.0f / 262144.0f;
    float mu = gnS1[b] * inv;
    float var = gnS2[b] * inv - mu * mu;
    float rs = rsqrtf(var + 1e-5f);
    float scale = rs * gamma[c];
    float shift = beta[c] - mu * scale;
    float4 v = *(const float4*)(y + e);
    float4 o;
    o.x = fmaxf(v.x * scale + shift, 0.0f);
    o.y = fmaxf(v.y * scale + shift, 0.0f);
    o.z = fmaxf(v.z * scale + shift, 0.0f);
    o.w = fmaxf(v.w * scale + shift, 0.0f);
    *(float4*)(out + e) = o;
}

extern "C" void kernel_launch(void* const* d_in, const int* in_sizes, int n_in,
                              void* d_out, int out_size, void* d_ws, size_t ws_size,
                              hipStream_t stream) {
    const float* fdm   = (const float*)d_in[0];
    const float* x     = (const float*)d_in[1];
    const float* Wf    = (const float*)d_in[2];
    const float* bfuse = (const float*)d_in[3];
    const float* gamma = (const float*)d_in[4];
    const float* beta  = (const float*)d_in[5];
    float* out = (float*)d_out;
    float* ws  = (float*)d_ws;

    // workspace layout (floats)
    float* y     = ws;                       // 4*64*4096 = 1048576
    float* rn    = ws + 1048576;             // 16384
    int*   sel   = (int*)(ws + 1048576 + 16384);   // 16384 ints
    int*   unsel = sel + 16384;              // 16384 ints
    int*   selN  = unsel + 16384;            // 4
    int*   unselN= selN + 4;                 // 4
    float* gnS1  = (float*)(unselN + 4);     // 4
    float* gnS2  = gnS1 + 4;                 // 4

    float* smOut = out + 1048576;            // second output, also conv input scale map

    k_pool<<<dim3(4), dim3(256), 0, stream>>>(fdm, sel, unsel, selN, unselN, gnS1, gnS2);
    k_norm<<<dim3(64), dim3(256), 0, stream>>>(x, rn, smOut);
    k_cosmax<<<dim3(16, 4), dim3(256), 0, stream>>>(x, rn, sel, unsel, selN, unselN, smOut);
    k_conv<<<dim3(64, 2, 4), dim3(256), 0, stream>>>(x, Wf, bfuse, smOut, y, gnS1, gnS2);
    k_gn<<<dim3(1024), dim3(256), 0, stream>>>(y, gnS1, gnS2, gamma, beta, out);
}

// Round 2
// 181.730 us; speedup vs baseline: 1.8316x; 1.8316x over previous
//
#include <hip/hip_runtime.h>
#include <math.h>

// Problem constants: b=4, f=64, h=w=64, HW=4096
// Inputs: fdm [4,1,128,128], x [4,64,64,64], W_fuse [64,128,3,3], b_fuse [64], gamma [64], beta [64]
// Outputs concatenated: x0 [4,64,64,64] (1048576 f32) then sm [4,1,64,64] (16384 f32)

#define HW 4096
#define NCH 64

// ---------------- K1: 2x2 max pool + per-batch max + threshold + unsel compaction ----------------
// grid 4 blocks (one per batch), 256 threads.
__global__ void k_pool(const float* __restrict__ fdm, float* __restrict__ pooledOut,
                       float* __restrict__ threOut, int* __restrict__ unsel, int* __restrict__ unselN,
                       float* __restrict__ gnS1, float* __restrict__ gnS2) {
    const int b = blockIdx.x;
    const int t = threadIdx.x;
    __shared__ float pooled[4096];
    __shared__ float red[256];
    __shared__ int cnt;
    __shared__ float thre_s;
    const float* fb = fdm + b * 16384;
    float lmax = -1.0f;
    // each iteration: 2 float4 loads -> 2 pooled outputs (cols 2*j2, 2*j2+1 of row i)
#pragma unroll
    for (int it = 0; it < 8; ++it) {
        int id2 = it * 256 + t;          // pooled-pair index 0..2047
        int i = id2 >> 5;                // pooled row 0..63
        int j2 = id2 & 31;               // pair-of-cols index 0..31
        const float* base = fb + i * 256 + j2 * 4;   // row 2i, col 4*j2
        float4 a = *(const float4*)base;
        float4 c = *(const float4*)(base + 128);     // row 2i+1
        float p0 = fmaxf(fmaxf(a.x, a.y), fmaxf(c.x, c.y));
        float p1 = fmaxf(fmaxf(a.z, a.w), fmaxf(c.z, c.w));
        pooled[i * 64 + j2 * 2]     = p0;
        pooled[i * 64 + j2 * 2 + 1] = p1;
        lmax = fmaxf(lmax, fmaxf(p0, p1));
    }
    red[t] = lmax;
    __syncthreads();
    for (int s = 128; s > 0; s >>= 1) {
        if (t < s) red[t] = fmaxf(red[t], red[t + s]);
        __syncthreads();
    }
    if (t == 0) {
        thre_s = fminf(0.5f, red[0] / 3.0f);   // match reference fp32 rounding exactly
        cnt = 0;
        gnS1[b] = 0.0f; gnS2[b] = 0.0f;        // zero GN accumulators (ws is poisoned)
    }
    __syncthreads();
    const float th = thre_s;
    // write pooled map to global (coalesced float4) + compact only the UNSELECTED (~50/batch)
#pragma unroll
    for (int it = 0; it < 4; ++it) {
        int idx = (it * 256 + t) * 4;
        *(float4*)(pooledOut + b * 4096 + idx) = *(const float4*)(pooled + idx);
    }
    for (int idx = t; idx < 4096; idx += 256) {
        if (!(pooled[idx] >= th)) {
            int pos = atomicAdd(&cnt, 1);
            unsel[b * 4096 + pos] = idx;
        }
    }
    __syncthreads();
    if (t == 0) { unselN[b] = cnt; threOut[b] = th; }
}

// ---------------- K2: per-position inverse norms + default sm = 1.0 ----------------
// grid 256 blocks x 256 threads; block covers 64 positions, 4 waves split the 64 channels.
__global__ void k_norm(const float* __restrict__ x, float* __restrict__ rn, float* __restrict__ smOut) {
    __shared__ float s_part[4][64];
    const int t = threadIdx.x;
    const int wv = t >> 6;
    const int l = t & 63;
    const int b = blockIdx.x >> 6;
    const int pbase = (blockIdx.x & 63) * 64;
    const float* xp = x + b * (NCH * HW) + pbase + l;
    float s0 = 0.f, s1 = 0.f, s2 = 0.f, s3 = 0.f;
#pragma unroll
    for (int i = 0; i < 16; i += 4) {
        int c = wv * 16 + i;
        float a0 = xp[(c + 0) * HW];
        float a1 = xp[(c + 1) * HW];
        float a2 = xp[(c + 2) * HW];
        float a3 = xp[(c + 3) * HW];
        s0 += a0 * a0; s1 += a1 * a1; s2 += a2 * a2; s3 += a3 * a3;
    }
    s_part[wv][l] = (s0 + s1) + (s2 + s3);
    __syncthreads();
    if (t < 64) {
        float ss = s_part[0][l] + s_part[1][l] + s_part[2][l] + s_part[3][l];
        int g = b * HW + pbase + l;
        rn[g] = 1.0f / fmaxf(sqrtf(ss), 1e-8f);
        smOut[g] = 1.0f;   // selected positions: diagonal cosine = 1 -> sm = 1
    }
}

// ---------------- K3: for unselected q, sm = (max over selected p of cos)/2 + 0.5 ----------------
// grid (64, 4): one block per unselected q (qi-strided). Threads sweep ALL p coalesced,
// masking with pooled[p] >= thre (same predicate as reference's selected set).
__global__ __launch_bounds__(256) void k_cosmax(const float* __restrict__ x, const float* __restrict__ rn,
                         const float* __restrict__ pooledMap, const float* __restrict__ threArr,
                         const int* __restrict__ unsel, const int* __restrict__ unselN,
                         float* __restrict__ smOut) {
    const int b = blockIdx.y;
    const int t = threadIdx.x;
    const int nu = unselN[b];
    __shared__ float s_xq[64];
    __shared__ float s_red[4];
    const float* xb = x + b * (NCH * HW);
    const float* rb = rn + b * HW;
    const float* pb = pooledMap + b * HW;
    const float th = threArr[b];
    const float4* s_xq4 = (const float4*)s_xq;
    for (int qi = blockIdx.x; qi < nu; qi += 64) {
        const int q = unsel[b * 4096 + qi];
        if (t < 64) s_xq[t] = xb[t * HW + q];
        __syncthreads();
        float best = -INFINITY;
#pragma unroll
        for (int j = 0; j < 4; ++j) {
            const int p0 = 4 * t + j * 1024;
            float d0 = 0.f, d1 = 0.f, d2 = 0.f, d3 = 0.f;
#pragma unroll 4
            for (int c4 = 0; c4 < 16; ++c4) {
                float4 wq = s_xq4[c4];
                const float* xc = xb + (4 * c4) * HW + p0;
                float4 v0 = *(const float4*)(xc);
                float4 v1 = *(const float4*)(xc + HW);
                float4 v2 = *(const float4*)(xc + 2 * HW);
                float4 v3 = *(const float4*)(xc + 3 * HW);
                d0 += v0.x * wq.x + v1.x * wq.y + v2.x * wq.z + v3.x * wq.w;
                d1 += v0.y * wq.x + v1.y * wq.y + v2.y * wq.z + v3.y * wq.w;
                d2 += v0.z * wq.x + v1.z * wq.y + v2.z * wq.z + v3.z * wq.w;
                d3 += v0.w * wq.x + v1.w * wq.y + v2.w * wq.z + v3.w * wq.w;
            }
            float sc;
            sc = (pb[p0 + 0] >= th) ? d0 * rb[p0 + 0] : -INFINITY; best = fmaxf(best, sc);
            sc = (pb[p0 + 1] >= th) ? d1 * rb[p0 + 1] : -INFINITY; best = fmaxf(best, sc);
            sc = (pb[p0 + 2] >= th) ? d2 * rb[p0 + 2] : -INFINITY; best = fmaxf(best, sc);
            sc = (pb[p0 + 3] >= th) ? d3 * rb[p0 + 3] : -INFINITY; best = fmaxf(best, sc);
        }
        // wave reduce (64 lanes), then combine 4 waves via LDS
#pragma unroll
        for (int off = 32; off > 0; off >>= 1) best = fmaxf(best, __shfl_xor(best, off));
        if ((t & 63) == 0) s_red[t >> 6] = best;
        __syncthreads();
        if (t == 0) {
            float m = fmaxf(fmaxf(s_red[0], s_red[1]), fmaxf(s_red[2], s_red[3]));
            smOut[b * HW + q] = m * rb[q] * 0.5f + 0.5f;
        }
        __syncthreads();   // protect s_xq / s_red before next qi
    }
}

// ---------------- K4: direct conv 3x3 (128->64) + bias, with GN partial sums via atomics ----------------
// grid: (h=64, split=2, b=4); block 256. Each block: 32 oc x 64 w for one row h.
// Thread: 2 oc x 4 w. ic chunks of 16 staged in LDS.
__global__ __launch_bounds__(256) void k_conv(const float* __restrict__ x, const float* __restrict__ W,
                                              const float* __restrict__ bfuse, const float* __restrict__ smAll,
                                              float* __restrict__ y, float* __restrict__ gnS1, float* __restrict__ gnS2) {
    const int h = blockIdx.x;
    const int split = blockIdx.y;
    const int b = blockIdx.z;
    __shared__ float in_t[16][3][68];     // ic x row x (66 cols, padded to 68)
    __shared__ float w_t[32][196];        // [oc][ic*12 + k]
    __shared__ float red1[256];
    __shared__ float red2[256];
    const int t = threadIdx.x;
    const int w4 = (t & 15) * 4;
    const int ocl = (t >> 4) * 2;
    const int ocg = split * 32 + ocl;
    const float* xb = x + b * (NCH * HW);
    const float* smb = smAll + b * HW;

    float acc0[4], acc1[4];
    const float bi0 = bfuse[ocg], bi1 = bfuse[ocg + 1];
#pragma unroll
    for (int j = 0; j < 4; ++j) { acc0[j] = bi0; acc1[j] = bi1; }

    for (int chunk = 0; chunk < 8; ++chunk) {
        __syncthreads();
        for (int idx = t; idx < 3168; idx += 256) {
            int ic = idx / 198;
            int rem = idx - ic * 198;
            int r = rem / 66;
            int tc = rem - r * 66;
            int icg = chunk * 16 + ic;
            int hh = h + r - 1;
            int cin = tc - 1;
            float v = 0.0f;
            if ((unsigned)hh < 64u && (unsigned)cin < 64u) {
                int sp = hh * 64 + cin;
                v = (icg < 64) ? smb[sp] * xb[icg * HW + sp] : xb[(icg - 64) * HW + sp];
            }
            in_t[ic][r][tc] = v;
        }
        for (int idx = t; idx < 4608; idx += 256) {
            int oc = idx / 144;
            int rem = idx - oc * 144;
            int ic = rem / 9;
            int k = rem - ic * 9;
            w_t[oc][ic * 12 + k] = W[(split * 32 + oc) * 1152 + (chunk * 16 + ic) * 9 + k];
        }
        __syncthreads();
#pragma unroll
        for (int ic = 0; ic < 16; ++ic) {
            float iv[3][6];
#pragma unroll
            for (int r = 0; r < 3; ++r) {
                const float* row = &in_t[ic][r][0];
                float4 v = *(const float4*)(row + w4);
                iv[r][0] = v.x; iv[r][1] = v.y; iv[r][2] = v.z; iv[r][3] = v.w;
                iv[r][4] = row[w4 + 4]; iv[r][5] = row[w4 + 5];
            }
            float wv0[9], wv1[9];
            {
                const float* wp = &w_t[ocl][ic * 12];
                float4 a = *(const float4*)wp;
                float4 bq = *(const float4*)(wp + 4);
                wv0[0] = a.x; wv0[1] = a.y; wv0[2] = a.z; wv0[3] = a.w;
                wv0[4] = bq.x; wv0[5] = bq.y; wv0[6] = bq.z; wv0[7] = bq.w;
                wv0[8] = wp[8];
            }
            {
                const float* wp = &w_t[ocl + 1][ic * 12];
                float4 a = *(const float4*)wp;
                float4 bq = *(const float4*)(wp + 4);
                wv1[0] = a.x; wv1[1] = a.y; wv1[2] = a.z; wv1[3] = a.w;
                wv1[4] = bq.x; wv1[5] = bq.y; wv1[6] = bq.z; wv1[7] = bq.w;
                wv1[8] = wp[8];
            }
#pragma unroll
            for (int r = 0; r < 3; ++r) {
#pragma unroll
                for (int s = 0; s < 3; ++s) {
                    float w0 = wv0[r * 3 + s];
                    float w1 = wv1[r * 3 + s];
#pragma unroll
                    for (int j = 0; j < 4; ++j) {
                        acc0[j] += w0 * iv[r][j + s];
                        acc1[j] += w1 * iv[r][j + s];
                    }
                }
            }
        }
    }
    const int sp = h * 64 + w4;
    float4 o0 = make_float4(acc0[0], acc0[1], acc0[2], acc0[3]);
    float4 o1 = make_float4(acc1[0], acc1[1], acc1[2], acc1[3]);
    *(float4*)(y + (b * 64 + ocg) * HW + sp) = o0;
    *(float4*)(y + (b * 64 + ocg + 1) * HW + sp) = o1;
    float s1 = 0.f, s2 = 0.f;
#pragma unroll
    for (int j = 0; j < 4; ++j) {
        s1 += acc0[j] + acc1[j];
        s2 += acc0[j] * acc0[j] + acc1[j] * acc1[j];
    }
    red1[t] = s1; red2[t] = s2;
    __syncthreads();
    for (int s = 128; s > 0; s >>= 1) {
        if (t < s) { red1[t] += red1[t + s]; red2[t] += red2[t + s]; }
        __syncthreads();
    }
    if (t == 0) {
        atomicAdd(&gnS1[b], red1[0]);
        atomicAdd(&gnS2[b], red2[0]);
    }
}

// ---------------- K5: GroupNorm(1 group) + affine + ReLU ----------------
__global__ void k_gn(const float* __restrict__ y, const float* __restrict__ gnS1, const float* __restrict__ gnS2,
                     const float* __restrict__ gamma, const float* __restrict__ beta, float* __restrict__ out) {
    const int e = (blockIdx.x * 256 + threadIdx.x) * 4;
    const int b = e >> 18;
    const int c = (e >> 12) & 63;
    const float inv = 1.0f / 262144.0f;
    float mu = gnS1[b] * inv;
    float var = gnS2[b] * inv - mu * mu;
    float rs = rsqrtf(var + 1e-5f);
    float scale = rs * gamma[c];
    float shift = beta[c] - mu * scale;
    float4 v = *(const float4*)(y + e);
    float4 o;
    o.x = fmaxf(v.x * scale + shift, 0.0f);
    o.y = fmaxf(v.y * scale + shift, 0.0f);
    o.z = fmaxf(v.z * scale + shift, 0.0f);
    o.w = fmaxf(v.w * scale + shift, 0.0f);
    *(float4*)(out + e) = o;
}

extern "C" void kernel_launch(void* const* d_in, const int* in_sizes, int n_in,
                              void* d_out, int out_size, void* d_ws, size_t ws_size,
                              hipStream_t stream) {
    const float* fdm   = (const float*)d_in[0];
    const float* x     = (const float*)d_in[1];
    const float* Wf    = (const float*)d_in[2];
    const float* bfuse = (const float*)d_in[3];
    const float* gamma = (const float*)d_in[4];
    const float* beta  = (const float*)d_in[5];
    float* out = (float*)d_out;
    float* ws  = (float*)d_ws;

    // workspace layout (floats)
    float* y       = ws;                         // 1048576
    float* rn      = ws + 1048576;               // 16384
    float* pooledM = ws + 1048576 + 16384;       // 16384
    float* thre    = pooledM + 16384;            // 4
    int*   unsel   = (int*)(thre + 4);           // 16384 ints
    int*   unselN  = unsel + 16384;              // 4
    float* gnS1    = (float*)(unselN + 4);       // 4
    float* gnS2    = gnS1 + 4;                   // 4

    float* smOut = out + 1048576;                // second output, also conv input scale map

    k_pool<<<dim3(4), dim3(256), 0, stream>>>(fdm, pooledM, thre, unsel, unselN, gnS1, gnS2);
    k_norm<<<dim3(256), dim3(256), 0, stream>>>(x, rn, smOut);
    k_cosmax<<<dim3(64, 4), dim3(256), 0, stream>>>(x, rn, pooledM, thre, unsel, unselN, smOut);
    k_conv<<<dim3(64, 2, 4), dim3(256), 0, stream>>>(x, Wf, bfuse, smOut, y, gnS1, gnS2);
    k_gn<<<dim3(1024), dim3(256), 0, stream>>>(y, gnS1, gnS2, gamma, beta, out);
}

// Round 3
// 133.290 us; speedup vs baseline: 2.4972x; 1.3634x over previous
//
#include <hip/hip_runtime.h>
#include <math.h>

// Problem constants: b=4, f=64, h=w=64, HW=4096
// Inputs: fdm [4,1,128,128], x [4,64,64,64], W_fuse [64,128,3,3], b_fuse [64], gamma [64], beta [64]
// Outputs concatenated: x0 [4,64,64,64] (1048576 f32) then sm [4,1,64,64] (16384 f32)

#define HW 4096
#define NCH 64

typedef __attribute__((ext_vector_type(8))) short short8;
typedef __attribute__((ext_vector_type(4))) float f32x4;

static __device__ __forceinline__ ushort f2bf(float f) {
    unsigned u = __float_as_uint(f);
    unsigned r = (u + 0x7fffu + ((u >> 16) & 1u)) >> 16;   // RNE
    return (ushort)r;
}
static __device__ __forceinline__ float bf2f(ushort h) {
    return __uint_as_float(((unsigned)h) << 16);
}

// ---------------- K1: 2x2 max pool + per-batch max + threshold + unsel compaction ----------------
__global__ void k_pool(const float* __restrict__ fdm, float* __restrict__ pooledOut,
                       float* __restrict__ threOut, int* __restrict__ unsel, int* __restrict__ unselN,
                       float* __restrict__ gnS1, float* __restrict__ gnS2) {
    const int b = blockIdx.x;
    const int t = threadIdx.x;
    __shared__ float pooled[4096];
    __shared__ float red[256];
    __shared__ int cnt;
    __shared__ float thre_s;
    const float* fb = fdm + b * 16384;
    float lmax = -1.0f;
#pragma unroll
    for (int it = 0; it < 8; ++it) {
        int id2 = it * 256 + t;
        int i = id2 >> 5;
        int j2 = id2 & 31;
        const float* base = fb + i * 256 + j2 * 4;
        float4 a = *(const float4*)base;
        float4 c = *(const float4*)(base + 128);
        float p0 = fmaxf(fmaxf(a.x, a.y), fmaxf(c.x, c.y));
        float p1 = fmaxf(fmaxf(a.z, a.w), fmaxf(c.z, c.w));
        pooled[i * 64 + j2 * 2]     = p0;
        pooled[i * 64 + j2 * 2 + 1] = p1;
        lmax = fmaxf(lmax, fmaxf(p0, p1));
    }
    red[t] = lmax;
    __syncthreads();
    for (int s = 128; s > 0; s >>= 1) {
        if (t < s) red[t] = fmaxf(red[t], red[t + s]);
        __syncthreads();
    }
    if (t == 0) {
        thre_s = fminf(0.5f, red[0] / 3.0f);
        cnt = 0;
        gnS1[b] = 0.0f; gnS2[b] = 0.0f;
    }
    __syncthreads();
    const float th = thre_s;
#pragma unroll
    for (int it = 0; it < 4; ++it) {
        int idx = (it * 256 + t) * 4;
        *(float4*)(pooledOut + b * 4096 + idx) = *(const float4*)(pooled + idx);
    }
    for (int idx = t; idx < 4096; idx += 256) {
        if (!(pooled[idx] >= th)) {
            int pos = atomicAdd(&cnt, 1);
            unsel[b * 4096 + pos] = idx;
        }
    }
    __syncthreads();
    if (t == 0) { unselN[b] = cnt; threOut[b] = th; }
}

// ---------------- K2: per-position inverse norms + default sm = 1.0 ----------------
__global__ void k_norm(const float* __restrict__ x, float* __restrict__ rn, float* __restrict__ smOut) {
    __shared__ float s_part[4][64];
    const int t = threadIdx.x;
    const int wv = t >> 6;
    const int l = t & 63;
    const int b = blockIdx.x >> 6;
    const int pbase = (blockIdx.x & 63) * 64;
    const float* xp = x + b * (NCH * HW) + pbase + l;
    float s0 = 0.f, s1 = 0.f, s2 = 0.f, s3 = 0.f;
#pragma unroll
    for (int i = 0; i < 16; i += 4) {
        int c = wv * 16 + i;
        float a0 = xp[(c + 0) * HW];
        float a1 = xp[(c + 1) * HW];
        float a2 = xp[(c + 2) * HW];
        float a3 = xp[(c + 3) * HW];
        s0 += a0 * a0; s1 += a1 * a1; s2 += a2 * a2; s3 += a3 * a3;
    }
    s_part[wv][l] = (s0 + s1) + (s2 + s3);
    __syncthreads();
    if (t < 64) {
        float ss = s_part[0][l] + s_part[1][l] + s_part[2][l] + s_part[3][l];
        int g = b * HW + pbase + l;
        rn[g] = 1.0f / fmaxf(sqrtf(ss), 1e-8f);
        smOut[g] = 1.0f;
    }
}

// ---------------- K3: for unselected q, sm = (max over selected p of cos)/2 + 0.5 ----------------
__global__ __launch_bounds__(256) void k_cosmax(const float* __restrict__ x, const float* __restrict__ rn,
                         const float* __restrict__ pooledMap, const float* __restrict__ threArr,
                         const int* __restrict__ unsel, const int* __restrict__ unselN,
                         float* __restrict__ smOut) {
    const int b = blockIdx.y;
    const int t = threadIdx.x;
    const int nu = unselN[b];
    __shared__ float s_xq[64];
    __shared__ float s_red[4];
    const float* xb = x + b * (NCH * HW);
    const float* rb = rn + b * HW;
    const float* pb = pooledMap + b * HW;
    const float th = threArr[b];
    const float4* s_xq4 = (const float4*)s_xq;
    for (int qi = blockIdx.x; qi < nu; qi += 64) {
        const int q = unsel[b * 4096 + qi];
        if (t < 64) s_xq[t] = xb[t * HW + q];
        __syncthreads();
        float best = -INFINITY;
#pragma unroll
        for (int j = 0; j < 4; ++j) {
            const int p0 = 4 * t + j * 1024;
            float d0 = 0.f, d1 = 0.f, d2 = 0.f, d3 = 0.f;
#pragma unroll 4
            for (int c4 = 0; c4 < 16; ++c4) {
                float4 wq = s_xq4[c4];
                const float* xc = xb + (4 * c4) * HW + p0;
                float4 v0 = *(const float4*)(xc);
                float4 v1 = *(const float4*)(xc + HW);
                float4 v2 = *(const float4*)(xc + 2 * HW);
                float4 v3 = *(const float4*)(xc + 3 * HW);
                d0 += v0.x * wq.x + v1.x * wq.y + v2.x * wq.z + v3.x * wq.w;
                d1 += v0.y * wq.x + v1.y * wq.y + v2.y * wq.z + v3.y * wq.w;
                d2 += v0.z * wq.x + v1.z * wq.y + v2.z * wq.z + v3.z * wq.w;
                d3 += v0.w * wq.x + v1.w * wq.y + v2.w * wq.z + v3.w * wq.w;
            }
            float sc;
            sc = (pb[p0 + 0] >= th) ? d0 * rb[p0 + 0] : -INFINITY; best = fmaxf(best, sc);
            sc = (pb[p0 + 1] >= th) ? d1 * rb[p0 + 1] : -INFINITY; best = fmaxf(best, sc);
            sc = (pb[p0 + 2] >= th) ? d2 * rb[p0 + 2] : -INFINITY; best = fmaxf(best, sc);
            sc = (pb[p0 + 3] >= th) ? d3 * rb[p0 + 3] : -INFINITY; best = fmaxf(best, sc);
        }
#pragma unroll
        for (int off = 32; off > 0; off >>= 1) best = fmaxf(best, __shfl_xor(best, off));
        if ((t & 63) == 0) s_red[t >> 6] = best;
        __syncthreads();
        if (t == 0) {
            float m = fmaxf(fmaxf(s_red[0], s_red[1]), fmaxf(s_red[2], s_red[3]));
            smOut[b * HW + q] = m * rb[q] * 0.5f + 0.5f;
        }
        __syncthreads();
    }
}

// ---------------- K4a: prep input -> bf16, spatial-major [b][sp][128ic] (cat = [sm*x, x]) ----------------
__global__ void k_prep_in(const float* __restrict__ x, const float* __restrict__ smAll,
                          ushort* __restrict__ inb) {
    const int u = blockIdx.x * 256 + threadIdx.x;   // 0..262143 = (b*4096+sp)*16 + g
    const int g = u & 15;
    const int sp = (u >> 4) & 4095;
    const int b = u >> 16;
    const float scale = (g < 8) ? smAll[b * 4096 + sp] : 1.0f;
    const float* xc = x + b * (NCH * HW) + ((g & 7) * 8) * HW + sp;
    ushort h[8];
#pragma unroll
    for (int j = 0; j < 8; ++j) h[j] = f2bf(xc[j * HW] * scale);
    *(uint4*)(inb + (size_t)u * 8) = *(const uint4*)h;
}

// ---------------- K4b: prep weights -> bf16 hi/lo, layout [tap][oc][ic128] ----------------
__global__ void k_prep_w(const float* __restrict__ W, ushort* __restrict__ wbh, ushort* __restrict__ wbl) {
    const int u = blockIdx.x * 256 + threadIdx.x;   // 0..9215 = tap*1024 + oc*16 + g
    if (u >= 9216) return;
    const int tap = u >> 10;
    const int rem = u & 1023;
    const int oc = rem >> 4;
    const int g = rem & 15;
    ushort hh[8], ll[8];
#pragma unroll
    for (int j = 0; j < 8; ++j) {
        int ic = g * 8 + j;
        float v = W[(oc * 128 + ic) * 9 + tap];
        ushort hb = f2bf(v);
        hh[j] = hb;
        ll[j] = f2bf(v - bf2f(hb));
    }
    *(uint4*)(wbh + (size_t)u * 8) = *(const uint4*)hh;
    *(uint4*)(wbl + (size_t)u * 8) = *(const uint4*)ll;
}

// ---------------- K5: MFMA implicit-GEMM conv 3x3 (128->64) + bias + GN partials ----------------
// grid (16 rowblk, 4 ocblk, 4 b), block 256 = 4 waves (one per output row).
// Wave computes 16 oc x 64 w via 4 C-tiles of 16x16. A = weights (m=oc), B = input (n=w).
__global__ __launch_bounds__(256) void k_conv_mfma(
    const ushort* __restrict__ inb, const ushort* __restrict__ wbh, const ushort* __restrict__ wbl,
    const float* __restrict__ bfuse, float* __restrict__ y,
    float* __restrict__ gnS1, float* __restrict__ gnS2) {
    const int rowblk = blockIdx.x;
    const int ocblk = blockIdx.y;
    const int b = blockIdx.z;
    const int t = threadIdx.x;
    const int lane = t & 63;
    const int wave = t >> 6;
    const int li = lane & 15;
    const int quad = lane >> 4;
    const int h0 = rowblk * 4;
    const int oc0 = ocblk * 16;

    __shared__ __align__(16) ushort s_in[6 * 66 * 40];   // [r][c][32ic pad40] halves
    __shared__ __align__(16) ushort s_wh[9 * 16 * 40];   // [tap][oc][32ic pad40]
    __shared__ __align__(16) ushort s_wl[9 * 16 * 40];
    __shared__ float red1[256];
    __shared__ float red2[256];

    f32x4 acc[4];
#pragma unroll
    for (int j = 0; j < 4; ++j) acc[j] = (f32x4){0.f, 0.f, 0.f, 0.f};

    for (int chunk = 0; chunk < 4; ++chunk) {
        const int ic0 = chunk * 32;
        __syncthreads();
        // stage input slab: rows h0-1..h0+4, cols -1..64, 32 ic (4x16B parts per cell)
        for (int idx = t; idx < 1584; idx += 256) {
            int part = idx & 3;
            int cell = idx >> 2;
            int r = cell / 66;
            int c = cell - r * 66;
            int h = h0 + r - 1;
            int w = c - 1;
            uint4 v = make_uint4(0u, 0u, 0u, 0u);
            if ((unsigned)h < 64u && (unsigned)w < 64u) {
                v = *(const uint4*)(inb + ((size_t)(b * 4096 + h * 64 + w) * 128 + ic0 + part * 8));
            }
            *(uint4*)(s_in + (size_t)cell * 40 + part * 8) = v;
        }
        // stage weights: {hi,lo} x 9 taps x 16 oc x 4 parts
        for (int idx = t; idx < 1152; idx += 256) {
            int part = idx & 3;
            int uu = idx >> 2;              // hl*144 + tap*16 + o
            int hl = uu / 144;
            int rem = uu - hl * 144;
            int tap = rem >> 4;
            int o = rem & 15;
            const ushort* src = (hl ? wbl : wbh) + ((size_t)(tap * 64 + oc0 + o) * 128 + ic0 + part * 8);
            uint4 v = *(const uint4*)src;
            ushort* dst = (hl ? s_wl : s_wh) + ((size_t)(tap * 16 + o) * 40 + part * 8);
            *(uint4*)dst = v;
        }
        __syncthreads();
#pragma unroll
        for (int kh = 0; kh < 3; ++kh) {
            const int r = wave + kh;
#pragma unroll
            for (int kw = 0; kw < 3; ++kw) {
                const int tap = kh * 3 + kw;
                short8 ah = *(const short8*)(s_wh + (size_t)(tap * 16 + li) * 40 + quad * 8);
                short8 al = *(const short8*)(s_wl + (size_t)(tap * 16 + li) * 40 + quad * 8);
#pragma unroll
                for (int j = 0; j < 4; ++j) {
                    int c = j * 16 + li + kw;
                    short8 bv = *(const short8*)(s_in + ((size_t)(r * 66 + c) * 40 + quad * 8));
                    acc[j] = __builtin_amdgcn_mfma_f32_16x16x32_bf16(ah, bv, acc[j], 0, 0, 0);
                    acc[j] = __builtin_amdgcn_mfma_f32_16x16x32_bf16(al, bv, acc[j], 0, 0, 0);
                }
            }
        }
    }
    // epilogue: bias, store (coalesced: col=lane&15 is w), GN partial sums
    float bias[4];
#pragma unroll
    for (int reg = 0; reg < 4; ++reg) bias[reg] = bfuse[oc0 + quad * 4 + reg];
    float s1 = 0.f, s2 = 0.f;
    const int hrow = h0 + wave;
#pragma unroll
    for (int j = 0; j < 4; ++j) {
#pragma unroll
        for (int reg = 0; reg < 4; ++reg) {
            float v = acc[j][reg] + bias[reg];
            y[((size_t)(b * 64 + oc0 + quad * 4 + reg)) * HW + hrow * 64 + j * 16 + li] = v;
            s1 += v; s2 += v * v;
        }
    }
    red1[t] = s1; red2[t] = s2;
    __syncthreads();
    for (int s = 128; s > 0; s >>= 1) {
        if (t < s) { red1[t] += red1[t + s]; red2[t] += red2[t + s]; }
        __syncthreads();
    }
    if (t == 0) {
        atomicAdd(&gnS1[b], red1[0]);
        atomicAdd(&gnS2[b], red2[0]);
    }
}

// ---------------- K6: GroupNorm(1 group) + affine + ReLU, in-place on out ----------------
__global__ void k_gn(float* __restrict__ out, const float* __restrict__ gnS1, const float* __restrict__ gnS2,
                     const float* __restrict__ gamma, const float* __restrict__ beta) {
    const int e = (blockIdx.x * 256 + threadIdx.x) * 4;
    const int b = e >> 18;
    const int c = (e >> 12) & 63;
    const float inv = 1.0f / 262144.0f;
    float mu = gnS1[b] * inv;
    float var = gnS2[b] * inv - mu * mu;
    float rs = rsqrtf(var + 1e-5f);
    float scale = rs * gamma[c];
    float shift = beta[c] - mu * scale;
    float4 v = *(const float4*)(out + e);
    float4 o;
    o.x = fmaxf(v.x * scale + shift, 0.0f);
    o.y = fmaxf(v.y * scale + shift, 0.0f);
    o.z = fmaxf(v.z * scale + shift, 0.0f);
    o.w = fmaxf(v.w * scale + shift, 0.0f);
    *(float4*)(out + e) = o;
}

extern "C" void kernel_launch(void* const* d_in, const int* in_sizes, int n_in,
                              void* d_out, int out_size, void* d_ws, size_t ws_size,
                              hipStream_t stream) {
    const float* fdm   = (const float*)d_in[0];
    const float* x     = (const float*)d_in[1];
    const float* Wf    = (const float*)d_in[2];
    const float* bfuse = (const float*)d_in[3];
    const float* gamma = (const float*)d_in[4];
    const float* beta  = (const float*)d_in[5];
    float* out = (float*)d_out;
    float* ws  = (float*)d_ws;

    // workspace layout (floats)
    float* rn      = ws;                        // 16384
    float* pooledM = rn + 16384;                // 16384
    float* thre    = pooledM + 16384;           // 4
    int*   unsel   = (int*)(thre + 4);          // 16384 ints
    int*   unselN  = unsel + 16384;             // 4
    float* gnS1    = (float*)(unselN + 4);      // 4
    float* gnS2    = gnS1 + 4;                  // 4
    float* base2   = gnS2 + 4;                  // pad to 16B below
    size_t off = ((size_t)(base2 - ws) + 3) & ~(size_t)3;
    ushort* wbh = (ushort*)(ws + off);          // 73728 halves = 18432 floats
    ushort* wbl = wbh + 73728;                  // 73728 halves
    ushort* inb = wbl + 73728;                  // 2097152 halves = 4 MB

    float* yout  = out;                         // conv output lives in out[0..1M), GN in-place
    float* smOut = out + 1048576;               // second output; also feeds prep

    k_pool<<<dim3(4), dim3(256), 0, stream>>>(fdm, pooledM, thre, unsel, unselN, gnS1, gnS2);
    k_norm<<<dim3(256), dim3(256), 0, stream>>>(x, rn, smOut);
    k_cosmax<<<dim3(64, 4), dim3(256), 0, stream>>>(x, rn, pooledM, thre, unsel, unselN, smOut);
    k_prep_w<<<dim3(36), dim3(256), 0, stream>>>(Wf, wbh, wbl);
    k_prep_in<<<dim3(1024), dim3(256), 0, stream>>>(x, smOut, inb);
    k_conv_mfma<<<dim3(16, 4, 4), dim3(256), 0, stream>>>(inb, wbh, wbl, bfuse, yout, gnS1, gnS2);
    k_gn<<<dim3(1024), dim3(256), 0, stream>>>(yout, gnS1, gnS2, gamma, beta);
}